// Round 1
// baseline (163.744 us; speedup 1.0000x reference)
//
#include <hip/hip_runtime.h>

#define T_FRAMES 16384
#define N_MELS 128
#define N_FREQ 513
#define REPEAT 256
#define FRAMES_PER_BLOCK 64
#define NCHUNK 8
#define BLOCK_THREADS 512  // NCHUNK * FRAMES_PER_BLOCK / ... (8 f-chunks x 64 frames)

__global__ __launch_bounds__(512, 1) void mel2lpc_kernel(
    const float* __restrict__ mel,   // [128][16384]
    const float* __restrict__ B,     // [513][128] inv_mel_basis
    const float* __restrict__ lag,   // [5]
    float* __restrict__ out)         // [4][16384*256]
{
  __shared__ float W_s[5][N_FREQ];
  __shared__ float red[NCHUNK][5][FRAMES_PER_BLOCK];
  __shared__ float lp_s[4][FRAMES_PER_BLOCK];

  const int tid = threadIdx.x;
  const int t0 = blockIdx.x * FRAMES_PER_BLOCK;

  // ---- Phase 0: build combined cosine/lag-window/ifft-norm table ----
  // ac[k] = sum_f W[k][f] * power[f], W[k][f] = lag[k]*cf*cos(2*pi*k*f/1024)
  for (int idx = tid; idx < 5 * N_FREQ; idx += BLOCK_THREADS) {
    int k = idx / N_FREQ;
    int f = idx - k * N_FREQ;
    float cf = (f == 0 || f == N_FREQ - 1) ? (1.0f / 1024.0f) : (2.0f / 1024.0f);
    float c = cospif((float)(k * f) * (1.0f / 512.0f));  // cos(2*pi*k*f/1024)
    W_s[k][f] = lag[k] * cf * c;
  }
  __syncthreads();

  const int fl = tid & 63;                                   // frame within block
  const int fc = __builtin_amdgcn_readfirstlane(tid >> 6);   // wave-uniform f-chunk
  const int t = t0 + fl;

  // ---- Phase 1: x[m] = 10^mel[m,t] into registers (coalesced loads) ----
  float x[N_MELS];
#pragma unroll
  for (int m = 0; m < N_MELS; ++m) {
    x[m] = exp2f(mel[m * T_FRAMES + t] * 3.3219280948873623f);
  }

  // ---- Phase 2: fused matmul + clamp + square + cosine transform ----
  float acc0 = 0.f, acc1 = 0.f, acc2 = 0.f, acc3 = 0.f, acc4 = 0.f;
  const int fstart = fc * 64;
  const int fend = (fc == NCHUNK - 1) ? N_FREQ : fstart + 64;
#pragma unroll 2
  for (int f = fstart; f < fend; ++f) {
    const float* Br = B + f * N_MELS;  // wave-uniform address -> scalar loads
    float s = 0.0f;
#pragma unroll
    for (int m = 0; m < N_MELS; ++m) s = fmaf(Br[m], x[m], s);
    float lin = fmaxf(s, 1e-12f);
    float p = lin * lin;
    acc0 = fmaf(W_s[0][f], p, acc0);
    acc1 = fmaf(W_s[1][f], p, acc1);
    acc2 = fmaf(W_s[2][f], p, acc2);
    acc3 = fmaf(W_s[3][f], p, acc3);
    acc4 = fmaf(W_s[4][f], p, acc4);
  }
  red[fc][0][fl] = acc0;
  red[fc][1][fl] = acc1;
  red[fc][2][fl] = acc2;
  red[fc][3][fl] = acc3;
  red[fc][4][fl] = acc4;
  __syncthreads();

  // ---- Phase 3: reduce partials + Levinson-Durbin (wave 0, 1 lane/frame) ----
  if (tid < 64) {
    float ac[5];
#pragma unroll
    for (int k = 0; k < 5; ++k) {
      float s = 0.f;
#pragma unroll
      for (int c = 0; c < NCHUNK; ++c) s += red[c][k][tid];
      ac[k] = s;
    }
    float E = ac[0];
    float k0 = ac[1] / E;
    E *= fmaxf(1.0f - k0 * k0, 1e-5f);
    float l0 = -k0;

    float a1 = ac[2] + l0 * ac[1];
    float k1 = a1 / E;
    E *= fmaxf(1.0f - k1 * k1, 1e-5f);
    float m0 = l0 - k1 * l0;
    float m1 = -k1;

    float a2 = ac[3] + m0 * ac[2] + m1 * ac[1];
    float k2 = a2 / E;
    E *= fmaxf(1.0f - k2 * k2, 1e-5f);
    float n0 = m0 - k2 * m1;
    float n1 = m1 - k2 * m0;
    float n2 = -k2;

    float a3 = ac[4] + n0 * ac[3] + n1 * ac[2] + n2 * ac[1];
    float k3 = a3 / E;
    float o0 = n0 - k3 * n2;
    float o1 = n1 - k3 * n1;
    float o2 = n2 - k3 * n0;
    float o3 = -k3;

    // lpc = [o0,o1,o2,o3]; out row j = -lpc[3-j]
    lp_s[0][tid] = -o3;
    lp_s[1][tid] = -o2;
    lp_s[2][tid] = -o1;
    lp_s[3][tid] = -o0;
  }
  __syncthreads();

  // ---- Phase 4: repeat-expand write, coalesced float4 ----
  // per block: 4 rows x 64 frames x 256 reps = 16384 float4 stores
  float4* out4 = (float4*)out;
#pragma unroll
  for (int i = 0; i < 32; ++i) {
    int vid = i * BLOCK_THREADS + tid;   // 0..16383
    int j = vid >> 12;                   // output row 0..3
    int rem = vid & 4095;                // float4 index within row-chunk
    int tl = rem >> 6;                   // local frame 0..63 (wave-uniform)
    float v = lp_s[j][tl];
    float4 vv = make_float4(v, v, v, v);
    out4[(size_t)j * (T_FRAMES * REPEAT / 4) + (size_t)t0 * 64 + rem] = vv;
  }
}

extern "C" void kernel_launch(void* const* d_in, const int* in_sizes, int n_in,
                              void* d_out, int out_size, void* d_ws, size_t ws_size,
                              hipStream_t stream) {
  const float* mel = (const float*)d_in[0];
  const float* B   = (const float*)d_in[1];
  const float* lag = (const float*)d_in[2];
  float* out = (float*)d_out;
  mel2lpc_kernel<<<T_FRAMES / FRAMES_PER_BLOCK, BLOCK_THREADS, 0, stream>>>(mel, B, lag, out);
}